// Round 1
// baseline (154.165 us; speedup 1.0000x reference)
//
#include <hip/hip_runtime.h>

namespace {
constexpr int kN = 8192;
constexpr int kD = 64;
constexpr int kTile = 128;
constexpr int kTilesPerDim = kN / kTile;                    // 64
constexpr int kNumTileSlots = kTilesPerDim * kTilesPerDim;  // 4096
constexpr double kNumPairs = (double)kN * (double)(kN - 1) / 2.0;  // 33550336
}  // namespace

// One block = one 128x128 tile of the pair matrix (upper-triangular tiles only).
// LDS tiles are stored transposed with an XOR swizzle:
//   element (k,row) lives at  k*128 + (row ^ (k & ~3))
// which makes both the staging writes (4 x ds_write_b32, 2-way max) and the
// per-k fragment reads (ds_read_b128, 2-way max / broadcast) bank-conflict free.
__global__ __launch_bounds__(256, 2) void pair_loss_kernel(
    const float* __restrict__ feat, const int* __restrict__ tgt,
    float* __restrict__ partial) {
  const int bx = blockIdx.x;  // column tile
  const int by = blockIdx.y;  // row tile
  const int bid = by * kTilesPerDim + bx;
  const int tid = threadIdx.x;

  if (bx < by) {  // strictly lower-triangular tile: no pairs
    if (tid == 0) partial[bid] = 0.0f;
    return;
  }

  __shared__ float As[kD * kTile];  // 32 KB
  __shared__ float Bs[kD * kTile];  // 32 KB

  const float4* arow = (const float4*)(feat + (size_t)by * kTile * kD);
  const float4* brow = (const float4*)(feat + (size_t)bx * kTile * kD);

  // Stage 128 rows x 64 floats per tile: 2048 float4 chunks, 8 per thread.
#pragma unroll
  for (int t = 0; t < 8; ++t) {
    const int c = tid + t * 256;
    const int row = c >> 4;         // [0,128)
    const int kc = (c & 15) << 2;   // [0,64) multiple of 4
    const float4 va = arow[c];
    const float4 vb = brow[c];
    const int p = kc * kTile + (row ^ kc);  // (k&~3) == kc for k in [kc,kc+4)
    As[p] = va.x; As[p + kTile] = va.y; As[p + 2 * kTile] = va.z; As[p + 3 * kTile] = va.w;
    Bs[p] = vb.x; Bs[p + kTile] = vb.y; Bs[p + 2 * kTile] = vb.z; Bs[p + 3 * kTile] = vb.w;
  }
  __syncthreads();

  const int tx = tid & 15;
  const int ty = tid >> 4;
  const int ra = ty << 2;  // rows ra..ra+3 and ra+64..ra+67
  const int ca = tx << 2;  // cols ca..ca+3 and ca+64..ca+67

  float acc[8][8];
#pragma unroll
  for (int r = 0; r < 8; ++r)
#pragma unroll
    for (int c = 0; c < 8; ++c) acc[r][c] = 0.0f;

#pragma unroll 4
  for (int k = 0; k < kD; ++k) {
    const int f = k & ~3;
    const int base = k * kTile;
    const float4 a0 = *(const float4*)&As[base + (ra ^ f)];
    const float4 a1 = *(const float4*)&As[base + (ra ^ f) + 64];
    const float4 b0 = *(const float4*)&Bs[base + (ca ^ f)];
    const float4 b1 = *(const float4*)&Bs[base + (ca ^ f) + 64];
    const float a[8] = {a0.x, a0.y, a0.z, a0.w, a1.x, a1.y, a1.z, a1.w};
    const float b[8] = {b0.x, b0.y, b0.z, b0.w, b1.x, b1.y, b1.z, b1.w};
#pragma unroll
    for (int r = 0; r < 8; ++r)
#pragma unroll
      for (int c = 0; c < 8; ++c) acc[r][c] += a[r] * b[c];
  }

  // Epilogue: BCEWithLogits per pair, upper-triangle mask on diagonal tiles.
  int rowi[8], colj[8], tr[8], tc[8];
#pragma unroll
  for (int r = 0; r < 8; ++r) {
    rowi[r] = (r < 4) ? (ra + r) : (64 + ra + (r - 4));
    colj[r] = (r < 4) ? (ca + r) : (64 + ca + (r - 4));
  }
#pragma unroll
  for (int r = 0; r < 8; ++r) {
    tr[r] = tgt[by * kTile + rowi[r]];
    tc[r] = tgt[bx * kTile + colj[r]];
  }

  const bool diag = (bx == by);
  float lsum = 0.0f;
#pragma unroll
  for (int r = 0; r < 8; ++r) {
#pragma unroll
    for (int c = 0; c < 8; ++c) {
      const float x = acc[r][c];
      // loss = max(x,0) - x*y + log1p(exp(-|x|))
      float l = fmaxf(x, 0.0f) + __logf(1.0f + __expf(-fabsf(x)));
      if (tr[r] == tc[c]) l -= x;
      const bool valid = !diag || (colj[c] > rowi[r]);
      lsum += valid ? l : 0.0f;
    }
  }

  // Block reduction: wave shuffle, then cross-wave via reused LDS.
#pragma unroll
  for (int off = 32; off > 0; off >>= 1) lsum += __shfl_down(lsum, off);

  __syncthreads();  // all LDS reads of As are done; safe to reuse
  if ((tid & 63) == 0) As[tid >> 6] = lsum;
  __syncthreads();
  if (tid == 0) {
    const float inv = (float)(1.0 / kNumPairs);
    partial[bid] = (As[0] + As[1] + As[2] + As[3]) * inv;
  }
}

__global__ void reduce_kernel(const float* __restrict__ partial,
                              float* __restrict__ out) {
  __shared__ float ws[4];
  const int tid = threadIdx.x;
  float s = 0.0f;
  for (int i = tid; i < kNumTileSlots; i += 256) s += partial[i];
#pragma unroll
  for (int off = 32; off > 0; off >>= 1) s += __shfl_down(s, off);
  if ((tid & 63) == 0) ws[tid >> 6] = s;
  __syncthreads();
  if (tid == 0) out[0] = ws[0] + ws[1] + ws[2] + ws[3];
}

extern "C" void kernel_launch(void* const* d_in, const int* in_sizes, int n_in,
                              void* d_out, int out_size, void* d_ws,
                              size_t ws_size, hipStream_t stream) {
  const float* feat = (const float*)d_in[0];
  const int* tgt = (const int*)d_in[1];
  float* partial = (float*)d_ws;  // 4096 floats, every slot written each call

  dim3 grid(kTilesPerDim, kTilesPerDim);
  pair_loss_kernel<<<grid, 256, 0, stream>>>(feat, tgt, partial);
  reduce_kernel<<<1, 256, 0, stream>>>(partial, (float*)d_out);
}

// Round 2
// 87.646 us; speedup vs baseline: 1.7590x; 1.7590x over previous
//
#include <hip/hip_runtime.h>

typedef __attribute__((ext_vector_type(8))) short bf16x8;
typedef __attribute__((ext_vector_type(4))) float floatx4;

namespace {
constexpr int kN = 8192;
constexpr int kD = 64;                                      // feature dim
constexpr int kTile = 128;                                  // tile edge
constexpr int kTilesPerDim = kN / kTile;                    // 64
constexpr int kNumBlocks = kTilesPerDim * (kTilesPerDim + 1) / 2;  // 2080
constexpr double kNumPairs = (double)kN * (double)(kN - 1) / 2.0;  // 33550336
}  // namespace

// fp32 -> bf16, round-to-nearest-even
__device__ __forceinline__ short f2bf(float f) {
  unsigned u = __builtin_bit_cast(unsigned, f);
  unsigned r = u + 0x7FFFu + ((u >> 16) & 1u);
  return (short)(r >> 16);
}

__device__ __forceinline__ bf16x8 cvt8(const float4 f0, const float4 f1) {
  bf16x8 v;
  v[0] = f2bf(f0.x); v[1] = f2bf(f0.y); v[2] = f2bf(f0.z); v[3] = f2bf(f0.w);
  v[4] = f2bf(f1.x); v[5] = f2bf(f1.y); v[6] = f2bf(f1.z); v[7] = f2bf(f1.w);
  return v;
}

// One block = one 128x128 upper-triangular tile of the pair matrix.
// B-tile (the "column" rows of X) staged in LDS as bf16 with a 16B-chunk XOR
// swizzle (chunk' = chunk ^ (row&7)) so both staging writes and fragment
// ds_read_b128 are balanced across the 8 bank groups (min-cycle, no excess
// conflicts). A-fragments go straight from global (L2-resident) to registers.
__global__ __launch_bounds__(256, 4) void pair_loss_kernel(
    const float* __restrict__ feat, const int* __restrict__ tgt,
    float* __restrict__ partial) {
  __shared__ short Bs[kTile * kD];  // 16 KB bf16, swizzled
  __shared__ int Tcol[kTile];       // column targets
  __shared__ float Red[4];

  // Decode linear block id -> (by, bx) with by <= bx (upper-tri tile).
  int rem = blockIdx.x;
  int by = 0;
  while (rem >= kTilesPerDim - by) {
    rem -= kTilesPerDim - by;
    ++by;
  }
  const int bx = by + rem;

  const int tid = threadIdx.x;
  const int lane = tid & 63;
  const int w = tid >> 6;        // wave id 0..3 -> rows [w*32, w*32+32)
  const int quad = lane >> 4;    // 0..3
  const int l15 = lane & 15;
  const int l7 = lane & 7;

  // ---- Stage B tile (128 rows x 64 bf16) + column targets into LDS ----
  {
    const int c = tid & 7;    // 16B chunk = 8 elements
    const int r0 = tid >> 3;  // 0..31
#pragma unroll
    for (int i = 0; i < 4; ++i) {
      const int r = r0 + 32 * i;
      const float* src = feat + (size_t)(bx * kTile + r) * kD + c * 8;
      const float4 f0 = *(const float4*)src;
      const float4 f1 = *(const float4*)(src + 4);
      *(bf16x8*)&Bs[r * kD + ((c ^ (r & 7)) << 3)] = cvt8(f0, f1);
    }
    if (tid < kTile) Tcol[tid] = tgt[bx * kTile + tid];
  }

  // ---- A fragments: global -> bf16 registers (issued before the barrier) ----
  const int arow = by * kTile + w * 32;
  bf16x8 afrag[2][2];  // [row-block][k-step]
#pragma unroll
  for (int rb = 0; rb < 2; ++rb) {
    const int row = arow + rb * 16 + l15;
#pragma unroll
    for (int ks = 0; ks < 2; ++ks) {
      const float* src = feat + (size_t)row * kD + ks * 32 + quad * 8;
      afrag[rb][ks] = cvt8(*(const float4*)src, *(const float4*)(src + 4));
    }
  }

  // Row targets: 4 consecutive (quad*4 + reg) per lane per row-block.
  int trow[2][4];
#pragma unroll
  for (int rb = 0; rb < 2; ++rb) {
    const int4 t4 = *(const int4*)(tgt + arow + rb * 16 + quad * 4);
    trow[rb][0] = t4.x; trow[rb][1] = t4.y; trow[rb][2] = t4.z; trow[rb][3] = t4.w;
  }

  __syncthreads();

  const bool diag = (bx == by);
  float lsum = 0.0f;

#pragma unroll
  for (int cb = 0; cb < 8; ++cb) {
    const int R = cb * 16 + l15;  // B-side row of X (= sim column)
    const bf16x8 b0 = *(const bf16x8*)&Bs[R * kD + (((0 + quad) ^ l7) << 3)];
    const bf16x8 b1 = *(const bf16x8*)&Bs[R * kD + (((4 + quad) ^ l7) << 3)];
    floatx4 acc0 = {0.f, 0.f, 0.f, 0.f};
    floatx4 acc1 = {0.f, 0.f, 0.f, 0.f};
    acc0 = __builtin_amdgcn_mfma_f32_16x16x32_bf16(afrag[0][0], b0, acc0, 0, 0, 0);
    acc0 = __builtin_amdgcn_mfma_f32_16x16x32_bf16(afrag[0][1], b1, acc0, 0, 0, 0);
    acc1 = __builtin_amdgcn_mfma_f32_16x16x32_bf16(afrag[1][0], b0, acc1, 0, 0, 0);
    acc1 = __builtin_amdgcn_mfma_f32_16x16x32_bf16(afrag[1][1], b1, acc1, 0, 0, 0);

    const int tc = Tcol[R];
    const int col_l = cb * 16 + l15;
#pragma unroll
    for (int rb = 0; rb < 2; ++rb) {
      const floatx4 a = rb ? acc1 : acc0;
      const int row_l0 = w * 32 + rb * 16 + quad * 4;
#pragma unroll
      for (int reg = 0; reg < 4; ++reg) {
        const float x = a[reg];
        const bool same = (trow[rb][reg] == tc);
        const float z = same ? x : -x;
        // -log_sigmoid(z) = max(-z,0) + log1p(exp(-|z|))
        const float l = fmaxf(-z, 0.0f) + __logf(1.0f + __expf(-fabsf(z)));
        const bool valid = !diag || (col_l > row_l0 + reg);
        lsum += valid ? l : 0.0f;
      }
    }
  }

  // Block reduction.
#pragma unroll
  for (int off = 32; off > 0; off >>= 1) lsum += __shfl_down(lsum, off);
  if (lane == 0) Red[w] = lsum;
  __syncthreads();
  if (tid == 0) {
    const float inv = (float)(1.0 / kNumPairs);
    partial[blockIdx.x] = (Red[0] + Red[1] + Red[2] + Red[3]) * inv;
  }
}

__global__ void reduce_kernel(const float* __restrict__ partial,
                              float* __restrict__ out) {
  __shared__ float ws[4];
  const int tid = threadIdx.x;
  float s = 0.0f;
  for (int i = tid; i < kNumBlocks; i += 256) s += partial[i];
#pragma unroll
  for (int off = 32; off > 0; off >>= 1) s += __shfl_down(s, off);
  if ((tid & 63) == 0) ws[tid >> 6] = s;
  __syncthreads();
  if (tid == 0) out[0] = ws[0] + ws[1] + ws[2] + ws[3];
}

extern "C" void kernel_launch(void* const* d_in, const int* in_sizes, int n_in,
                              void* d_out, int out_size, void* d_ws,
                              size_t ws_size, hipStream_t stream) {
  const float* feat = (const float*)d_in[0];
  const int* tgt = (const int*)d_in[1];
  float* partial = (float*)d_ws;  // kNumBlocks floats, all written every call

  pair_loss_kernel<<<kNumBlocks, 256, 0, stream>>>(feat, tgt, partial);
  reduce_kernel<<<1, 256, 0, stream>>>(partial, (float*)d_out);
}

// Round 3
// 78.561 us; speedup vs baseline: 1.9624x; 1.1157x over previous
//
#include <hip/hip_runtime.h>

typedef __attribute__((ext_vector_type(8))) short bf16x8;
typedef __attribute__((ext_vector_type(4))) float floatx4;

namespace {
constexpr int kN = 8192;
constexpr int kD = 64;                                      // feature dim
constexpr int kTile = 128;                                  // tile edge
constexpr int kTilesPerDim = kN / kTile;                    // 64
constexpr int kNumBlocks = kTilesPerDim * (kTilesPerDim + 1) / 2;  // 2080
constexpr double kNumPairs = (double)kN * (double)(kN - 1) / 2.0;  // 33550336
// ln(1+e), e in [0,1]: Abramowitz-Stegun 4.1.43 degree-5, |err| <= 1e-5.
__device__ __constant__ float kA1 = 0.99949556f;
__device__ __constant__ float kA2 = -0.49190896f;
__device__ __constant__ float kA3 = 0.28947478f;
__device__ __constant__ float kA4 = -0.13606275f;
__device__ __constant__ float kA5 = 0.03215845f;
constexpr float kNegLog2e = -1.4426950408889634f;
}  // namespace

// fp32 -> bf16, round-to-nearest-even
__device__ __forceinline__ short f2bf(float f) {
  unsigned u = __builtin_bit_cast(unsigned, f);
  unsigned r = u + 0x7FFFu + ((u >> 16) & 1u);
  return (short)(r >> 16);
}

__device__ __forceinline__ bf16x8 cvt8(const float4 f0, const float4 f1) {
  bf16x8 v;
  v[0] = f2bf(f0.x); v[1] = f2bf(f0.y); v[2] = f2bf(f0.z); v[3] = f2bf(f0.w);
  v[4] = f2bf(f1.x); v[5] = f2bf(f1.y); v[6] = f2bf(f1.z); v[7] = f2bf(f1.w);
  return v;
}

__device__ __forceinline__ float fast_exp2(float t) {
#if __has_builtin(__builtin_amdgcn_exp2f)
  return __builtin_amdgcn_exp2f(t);
#else
  return exp2f(t);
#endif
}

// One block = one 128x128 upper-triangular tile of the pair matrix.
// Per pair:  loss = 0.5*x + 0.5*|x| + ln(1+e^{-|x|}) - y*x   (exact identity)
// so we accumulate 4 linear sums; ln(1+e) via one v_exp_f32 + 5 FMA poly.
// Diagonal tiles: tile is symmetric and the diagonal elements x_ii=|x_i|^2
// (y=1) contribute log1p(e^{-~64}) ~= 0, so strict-upper = full_tile/2 —
// no per-pair masking anywhere.
__global__ __launch_bounds__(256, 4) void pair_loss_kernel(
    const float* __restrict__ feat, const int* __restrict__ tgt,
    float* __restrict__ partial) {
  __shared__ short Bs[kTile * kD];  // 16 KB bf16, chunk-XOR swizzled
  __shared__ int Tcol[kTile];       // column targets
  __shared__ float Red[4];

  // Decode linear block id -> (by, bx), by <= bx: closed form + exact fixup.
  const int bid = blockIdx.x;
  int by;
  {
    float f = 0.5f * (129.0f - sqrtf(16641.0f - 8.0f * (float)bid));
    by = (int)f;
    by = by > 63 ? 63 : (by < 0 ? 0 : by);
    // start(b) = 64*b - b*(b-1)/2
    while (64 * (by + 1) - ((by + 1) * by) / 2 <= bid) ++by;
    while (64 * by - (by * (by - 1)) / 2 > bid) --by;
  }
  const int bx = by + (bid - (64 * by - (by * (by - 1)) / 2));

  const int tid = threadIdx.x;
  const int lane = tid & 63;
  const int w = tid >> 6;        // wave id 0..3 -> rows [w*32, w*32+32)
  const int quad = lane >> 4;    // 0..3
  const int l15 = lane & 15;
  const int l7 = lane & 7;

  // ---- Stage B tile (128 rows x 64 bf16) + column targets into LDS ----
  {
    const int c = tid & 7;    // 16B chunk = 8 elements
    const int r0 = tid >> 3;  // 0..31
#pragma unroll
    for (int i = 0; i < 4; ++i) {
      const int r = r0 + 32 * i;
      const float* src = feat + (size_t)(bx * kTile + r) * kD + c * 8;
      const float4 f0 = *(const float4*)src;
      const float4 f1 = *(const float4*)(src + 4);
      *(bf16x8*)&Bs[r * kD + ((c ^ (r & 7)) << 3)] = cvt8(f0, f1);
    }
    if (tid < kTile) Tcol[tid] = tgt[bx * kTile + tid];
  }

  // ---- A fragments: global -> bf16 registers (before the barrier) ----
  const int arow = by * kTile + w * 32;
  bf16x8 afrag[2][2];  // [row-block][k-step]
#pragma unroll
  for (int rb = 0; rb < 2; ++rb) {
    const int row = arow + rb * 16 + l15;
#pragma unroll
    for (int ks = 0; ks < 2; ++ks) {
      const float* src = feat + (size_t)row * kD + ks * 32 + quad * 8;
      afrag[rb][ks] = cvt8(*(const float4*)src, *(const float4*)(src + 4));
    }
  }

  // Row targets: 4 consecutive (quad*4 + reg) per lane per row-block.
  int trow[2][4];
#pragma unroll
  for (int rb = 0; rb < 2; ++rb) {
    const int4 t4 = *(const int4*)(tgt + arow + rb * 16 + quad * 4);
    trow[rb][0] = t4.x; trow[rb][1] = t4.y; trow[rb][2] = t4.z; trow[rb][3] = t4.w;
  }

  __syncthreads();

  float S_x = 0.0f, S_a = 0.0f, S_l = 0.0f, S_y = 0.0f;

#pragma unroll 2
  for (int cb = 0; cb < 8; ++cb) {
    const int R = cb * 16 + l15;  // B-side row of X (= sim column)
    const bf16x8 b0 = *(const bf16x8*)&Bs[R * kD + ((quad ^ l7) << 3)];
    const bf16x8 b1 = *(const bf16x8*)&Bs[R * kD + (((4 + quad) ^ l7) << 3)];
    floatx4 acc0 = {0.f, 0.f, 0.f, 0.f};
    floatx4 acc1 = {0.f, 0.f, 0.f, 0.f};
    acc0 = __builtin_amdgcn_mfma_f32_16x16x32_bf16(afrag[0][0], b0, acc0, 0, 0, 0);
    acc0 = __builtin_amdgcn_mfma_f32_16x16x32_bf16(afrag[0][1], b1, acc0, 0, 0, 0);
    acc1 = __builtin_amdgcn_mfma_f32_16x16x32_bf16(afrag[1][0], b0, acc1, 0, 0, 0);
    acc1 = __builtin_amdgcn_mfma_f32_16x16x32_bf16(afrag[1][1], b1, acc1, 0, 0, 0);

    const int tc = Tcol[R];
#pragma unroll
    for (int rb = 0; rb < 2; ++rb) {
      const floatx4 a = rb ? acc1 : acc0;
#pragma unroll
      for (int reg = 0; reg < 4; ++reg) {
        const float x = a[reg];
        S_x += x;
        S_a += fabsf(x);
        const float e = fast_exp2(kNegLog2e * fabsf(x));  // e^{-|x|}
        float h = fmaf(e, kA5, kA4);
        h = fmaf(e, h, kA3);
        h = fmaf(e, h, kA2);
        h = fmaf(e, h, kA1);
        S_l = fmaf(e, h, S_l);           // += ln(1+e)
        if (trow[rb][reg] == tc) S_y += x;
      }
    }
  }

  float lsum = 0.5f * (S_x + S_a) + S_l - S_y;

  // Block reduction.
#pragma unroll
  for (int off = 32; off > 0; off >>= 1) lsum += __shfl_down(lsum, off);
  if (lane == 0) Red[w] = lsum;
  __syncthreads();
  if (tid == 0) {
    const float scale =
        (float)(1.0 / kNumPairs) * ((bx == by) ? 0.5f : 1.0f);
    partial[bid] = (Red[0] + Red[1] + Red[2] + Red[3]) * scale;
  }
}

__global__ void reduce_kernel(const float* __restrict__ partial,
                              float* __restrict__ out) {
  __shared__ float ws[4];
  const int tid = threadIdx.x;
  float s = 0.0f;
  for (int i = tid; i < kNumBlocks; i += 256) s += partial[i];
#pragma unroll
  for (int off = 32; off > 0; off >>= 1) s += __shfl_down(s, off);
  if ((tid & 63) == 0) ws[tid >> 6] = s;
  __syncthreads();
  if (tid == 0) out[0] = ws[0] + ws[1] + ws[2] + ws[3];
}

extern "C" void kernel_launch(void* const* d_in, const int* in_sizes, int n_in,
                              void* d_out, int out_size, void* d_ws,
                              size_t ws_size, hipStream_t stream) {
  const float* feat = (const float*)d_in[0];
  const int* tgt = (const int*)d_in[1];
  float* partial = (float*)d_ws;  // kNumBlocks floats, all written every call

  pair_loss_kernel<<<kNumBlocks, 256, 0, stream>>>(feat, tgt, partial);
  reduce_kernel<<<1, 256, 0, stream>>>(partial, (float*)d_out);
}